// Round 1
// baseline (322.597 us; speedup 1.0000x reference)
//
#include <hip/hip_runtime.h>
#include <hip/hip_bf16.h>
#include <math.h>

// ---------------------------------------------------------------------------
// Q_Mlp: x0 -> int4-quant -> GEMM1(K=768) -> dequant+GELU+clip -> int4-quant
//        -> GEMM2(K=3072) -> dequant+bias -> out (f32)
// All matmul operands are integers in [-8,7]: exact in bf16, accumulation
// < 2^24 -> bf16 MFMA == exact integer matmul.
// Workspace layout (bytes):
//   [0,256)                 : means a1, a2 (f32)
//   [256, +25165824)        : xq  bf16 [16384][768]
//   [25166080, +4718592)    : wq1 bf16 [3072][768]
//   [29884672, +4718592)    : wq2 bf16 [768][3072]
//   [34603264, +100663296)  : hq  bf16 [16384][3072]
//   total ~135.3 MB
// ---------------------------------------------------------------------------

typedef __attribute__((ext_vector_type(8))) short short8;
typedef __attribute__((ext_vector_type(4))) float f32x4;

__device__ __forceinline__ void gload_lds16(const void* g, void* l) {
  __builtin_amdgcn_global_load_lds(
      (const __attribute__((address_space(1))) void*)g,
      (__attribute__((address_space(3))) void*)l, 16, 0, 0);
}

// quantize: round-half-even(clip(x/a, -8, 7)) -> bf16 bits (exact: small ints)
__device__ __forceinline__ unsigned short q4_bf16(float x, float a) {
  float t = x / a;
  t = fminf(fmaxf(t, -8.0f), 7.0f);
  t = rintf(t);  // RNE, matches np.round
  return (unsigned short)(__float_as_uint(t) >> 16);
}

// ---- means of alpha_a1 (768) and alpha_a2 (3072), f64 accumulate ----------
__global__ void means_k(const float* __restrict__ v1, int n1,
                        const float* __restrict__ v2, int n2,
                        float* __restrict__ out) {
  const float* src = blockIdx.x ? v2 : v1;
  const int n = blockIdx.x ? n2 : n1;
  __shared__ double red[256];
  double s = 0.0;
  for (int i = threadIdx.x; i < n; i += 256) s += (double)src[i];
  red[threadIdx.x] = s;
  __syncthreads();
  for (int st = 128; st > 0; st >>= 1) {
    if (threadIdx.x < st) red[threadIdx.x] += red[threadIdx.x + st];
    __syncthreads();
  }
  if (threadIdx.x == 0) out[blockIdx.x] = (float)(red[0] / (double)n);
}

// ---- quantize activations x0 -> xq bf16 -----------------------------------
__global__ void quant_x_k(const float* __restrict__ x,
                          unsigned short* __restrict__ xq,
                          const float* __restrict__ means, int n4) {
  int i = blockIdx.x * blockDim.x + threadIdx.x;
  if (i >= n4) return;
  const float a = means[0];
  float4 v = ((const float4*)x)[i];
  ushort4 o;
  o.x = q4_bf16(v.x, a);
  o.y = q4_bf16(v.y, a);
  o.z = q4_bf16(v.z, a);
  o.w = q4_bf16(v.w, a);
  ((ushort4*)xq)[i] = o;
}

// ---- quantize weights [R][C] with per-row alpha ---------------------------
__global__ void quant_w_k(const float* __restrict__ w,
                          const float* __restrict__ alpha,
                          unsigned short* __restrict__ wq, int C, int n4) {
  int i = blockIdx.x * blockDim.x + threadIdx.x;
  if (i >= n4) return;
  int row = (i * 4) / C;
  const float a = alpha[row];
  float4 v = ((const float4*)w)[i];
  ushort4 o;
  o.x = q4_bf16(v.x, a);
  o.y = q4_bf16(v.y, a);
  o.z = q4_bf16(v.z, a);
  o.w = q4_bf16(v.w, a);
  ((ushort4*)wq)[i] = o;
}

// ---- GEMM: C[M,N] = A[M,K] * B[N,K]^T, bf16 MFMA 16x16x32 -----------------
// 128x128 tile, BK=64, 256 threads (4 waves 2x2), m97-style 2-barrier loop.
// EPI==1: dequant(a1,alpha_w1)+bias -> gelu -> clip -> quant(a2) -> bf16 hq
// EPI==2: dequant(a2,alpha_w2)+bias -> f32 out
template <int EPI>
__global__ __launch_bounds__(256) void gemm_k(
    const unsigned short* __restrict__ A, const unsigned short* __restrict__ B,
    const float* __restrict__ alphaw, const float* __restrict__ bias,
    const float* __restrict__ means, unsigned short* __restrict__ out_h,
    float* __restrict__ out_f, int N, int K) {
  __shared__ __align__(16) unsigned short sA[128 * 64];
  __shared__ __align__(16) unsigned short sB[128 * 64];
  const int tid = threadIdx.x;
  const int w = tid >> 6;
  const int l = tid & 63;
  const int wm = w >> 1, wn = w & 1;
  const long bm0 = (long)blockIdx.y * 128;
  const long bn0 = (long)blockIdx.x * 128;

  f32x4 acc[4][4] = {};

  const int srow = l >> 3;        // row-within-chunk 0..7
  const int scol = (l & 7) * 8;   // starting element col (16B per lane)

  for (int kt = 0; kt < K; kt += 64) {
    __syncthreads();  // previous tile's LDS reads done
#pragma unroll
    for (int i = 0; i < 4; ++i) {
      const int c = w * 4 + i;          // chunk: 8 rows = 1KB of LDS
      const int row = c * 8 + srow;
      gload_lds16(A + (bm0 + row) * K + kt + scol, &sA[c * 512]);
      gload_lds16(B + (bn0 + row) * K + kt + scol, &sB[c * 512]);
    }
    __syncthreads();  // staging visible (compiler drains vmcnt)
#pragma unroll
    for (int kk = 0; kk < 2; ++kk) {
      short8 af[4], bg[4];
#pragma unroll
      for (int m = 0; m < 4; ++m)
        af[m] = *(const short8*)&sA[(wm * 64 + m * 16 + (l & 15)) * 64 +
                                    kk * 32 + (l >> 4) * 8];
#pragma unroll
      for (int n = 0; n < 4; ++n)
        bg[n] = *(const short8*)&sB[(wn * 64 + n * 16 + (l & 15)) * 64 +
                                    kk * 32 + (l >> 4) * 8];
#pragma unroll
      for (int m = 0; m < 4; ++m)
#pragma unroll
        for (int n = 0; n < 4; ++n)
          acc[m][n] = __builtin_amdgcn_mfma_f32_16x16x32_bf16(
              af[m], bg[n], acc[m][n], 0, 0, 0);
    }
  }

  const float a1 = means[0];
  const float a2 = means[1];
  const float deq = (EPI == 1) ? a1 : a2;

#pragma unroll
  for (int n = 0; n < 4; ++n) {
    const long cc = bn0 + wn * 64 + n * 16 + (l & 15);
    const float aw = alphaw[cc];
    const float bs = bias[cc];
#pragma unroll
    for (int m = 0; m < 4; ++m) {
#pragma unroll
      for (int rg = 0; rg < 4; ++rg) {
        const long r = bm0 + wm * 64 + m * 16 + (l >> 4) * 4 + rg;
        // match numpy rounding: separate mul,mul,add (no FMA contraction)
        float t = __fmul_rn(acc[m][n][rg], aw);
        t = __fmul_rn(t, deq);
        t = __fadd_rn(t, bs);
        if (EPI == 1) {
          // exact GELU: 0.5*x*(1+erf(x/sqrt(2)))
          float g = __fmul_rn(__fmul_rn(0.5f, t),
                              __fadd_rn(1.0f, erff(t * 0.70710678118654752f)));
          g = fminf(fmaxf(g, -10.0f), 10.0f);
          float qv = g / a2;
          qv = fminf(fmaxf(qv, -8.0f), 7.0f);
          qv = rintf(qv);
          out_h[r * N + cc] = (unsigned short)(__float_as_uint(qv) >> 16);
        } else {
          out_f[r * N + cc] = t;
        }
      }
    }
  }
}

extern "C" void kernel_launch(void* const* d_in, const int* in_sizes, int n_in,
                              void* d_out, int out_size, void* d_ws,
                              size_t ws_size, hipStream_t stream) {
  const float* x0 = (const float*)d_in[0];
  const float* w1 = (const float*)d_in[1];
  const float* b1 = (const float*)d_in[2];
  const float* aw1 = (const float*)d_in[3];
  const float* aa1 = (const float*)d_in[4];
  const float* w2 = (const float*)d_in[5];
  const float* b2 = (const float*)d_in[6];
  const float* aw2 = (const float*)d_in[7];
  const float* aa2 = (const float*)d_in[8];

  char* ws = (char*)d_ws;
  float* means = (float*)ws;
  unsigned short* xq = (unsigned short*)(ws + 256);
  unsigned short* wq1 = (unsigned short*)(ws + 25166080);
  unsigned short* wq2 = (unsigned short*)(ws + 29884672);
  unsigned short* hq = (unsigned short*)(ws + 34603264);

  // 1) means of alpha_a1 / alpha_a2
  means_k<<<2, 256, 0, stream>>>(aa1, 768, aa2, 3072, means);
  // 2) quantize activations and weights to bf16 integer values
  quant_x_k<<<12288, 256, 0, stream>>>(x0, xq, means, 3145728);
  quant_w_k<<<2304, 256, 0, stream>>>(w1, aw1, wq1, 768, 589824);
  quant_w_k<<<2304, 256, 0, stream>>>(w2, aw2, wq2, 3072, 589824);
  // 3) GEMM1 [16384,768]x[3072,768]^T + gelu + requant -> hq
  dim3 g1(24, 128);
  gemm_k<1><<<g1, 256, 0, stream>>>(xq, wq1, aw1, b1, means, hq, nullptr, 3072,
                                    768);
  // 4) GEMM2 [16384,3072]x[768,3072]^T + bias -> out f32
  dim3 g2(6, 128);
  gemm_k<2><<<g2, 256, 0, stream>>>(hq, wq2, aw2, b2, means, nullptr,
                                    (float*)d_out, 768, 3072);
}

// Round 2
// 199.267 us; speedup vs baseline: 1.6189x; 1.6189x over previous
//
#include <hip/hip_runtime.h>
#include <hip/hip_bf16.h>
#include <math.h>

// ---------------------------------------------------------------------------
// Q_Mlp: x0 -> int4-quant -> GEMM1(K=768) -> dequant+GELU+clip -> int4-quant
//        -> GEMM2(K=3072) -> dequant+bias -> out (f32)
// Quantized operands are integers in [-8,7]: exact in int8. i8 MFMA
// (16x16x64, 2x bf16 rate) with i32 accumulation (max |acc| < 2^18, exact).
// Workspace layout (bytes):
//   [0,256)              : means a1, a2, 1/a2 (f32)
//   [256, +12582912)     : xq  i8 [16384][768]
//   [12583168, +2359296) : wq1 i8 [3072][768]
//   [14942464, +2359296) : wq2 i8 [768][3072]
//   [17301760, +50331648): hq  i8 [16384][3072]
//   total ~67.6 MB
// ---------------------------------------------------------------------------

typedef __attribute__((ext_vector_type(4))) int i32x4;

__device__ __forceinline__ void gload_lds16(const void* g, void* l) {
  __builtin_amdgcn_global_load_lds(
      (const __attribute__((address_space(1))) void*)g,
      (__attribute__((address_space(3))) void*)l, 16, 0, 0);
}

// quantize: round-half-even(clip(x/a, -8, 7)) -> int in [-8,7]
__device__ __forceinline__ int q4_i8(float x, float a) {
  float t = x / a;  // IEEE div, matches numpy
  t = fminf(fmaxf(t, -8.0f), 7.0f);
  t = rintf(t);  // RNE, matches np.round
  return (int)t;
}

// branch-free erf approx (Abramowitz-Stegun 7.1.26, |err|<=1.5e-7)
__device__ __forceinline__ float erf_fast(float x) {
  float az = fabsf(x);
  float t = 1.0f / fmaf(0.3275911f, az, 1.0f);
  float p = fmaf(t, 1.061405429f, -1.453152027f);
  p = fmaf(t, p, 1.421413741f);
  p = fmaf(t, p, -0.284496736f);
  p = fmaf(t, p, 0.254829592f);
  p = p * t;
  float e = __expf(-az * az);
  float r = fmaf(-p, e, 1.0f);
  return copysignf(r, x);
}

// ---- means of alpha_a1 (768) and alpha_a2 (3072), f64 accumulate ----------
__global__ void means_k(const float* __restrict__ v1, int n1,
                        const float* __restrict__ v2, int n2,
                        float* __restrict__ out) {
  const float* src = blockIdx.x ? v2 : v1;
  const int n = blockIdx.x ? n2 : n1;
  __shared__ double red[256];
  double s = 0.0;
  for (int i = threadIdx.x; i < n; i += 256) s += (double)src[i];
  red[threadIdx.x] = s;
  __syncthreads();
  for (int st = 128; st > 0; st >>= 1) {
    if (threadIdx.x < st) red[threadIdx.x] += red[threadIdx.x + st];
    __syncthreads();
  }
  if (threadIdx.x == 0) {
    float m = (float)(red[0] / (double)n);
    out[blockIdx.x] = m;
    if (blockIdx.x == 1) out[2] = 1.0f / m;
  }
}

// ---- quantize activations x0 -> xq i8 -------------------------------------
__global__ void quant_x_k(const float* __restrict__ x,
                          unsigned* __restrict__ xq,
                          const float* __restrict__ means, int n4) {
  int i = blockIdx.x * blockDim.x + threadIdx.x;
  if (i >= n4) return;
  const float a = means[0];
  float4 v = ((const float4*)x)[i];
  unsigned u = (q4_i8(v.x, a) & 0xFF) | ((q4_i8(v.y, a) & 0xFF) << 8) |
               ((q4_i8(v.z, a) & 0xFF) << 16) | ((q4_i8(v.w, a) & 0xFF) << 24);
  xq[i] = u;
}

// ---- quantize weights [R][C] with per-row alpha ---------------------------
__global__ void quant_w_k(const float* __restrict__ w,
                          const float* __restrict__ alpha,
                          unsigned* __restrict__ wq, int C, int n4) {
  int i = blockIdx.x * blockDim.x + threadIdx.x;
  if (i >= n4) return;
  int row = (i * 4) / C;
  const float a = alpha[row];
  float4 v = ((const float4*)w)[i];
  unsigned u = (q4_i8(v.x, a) & 0xFF) | ((q4_i8(v.y, a) & 0xFF) << 8) |
               ((q4_i8(v.z, a) & 0xFF) << 16) | ((q4_i8(v.w, a) & 0xFF) << 24);
  wq[i] = u;
}

// ---- GEMM: C[M,N] = A[M,K] * B[N,K]^T, i8 MFMA 16x16x64, BK=128 -----------
// 128x128 tile, 256 threads (4 waves 2x2), 2-barrier loop, global_load_lds.
// EPI==1: dequant(a1,alpha_w1)+bias -> gelu -> clip -> quant(a2) -> i8 hq
// EPI==2: dequant(a2,alpha_w2)+bias -> f32 out (bit-exact chain)
template <int EPI>
__global__ __launch_bounds__(256) void gemm_k(
    const signed char* __restrict__ A, const signed char* __restrict__ B,
    const float* __restrict__ alphaw, const float* __restrict__ bias,
    const float* __restrict__ means, signed char* __restrict__ out_b,
    float* __restrict__ out_f, int N, int K) {
  __shared__ __align__(16) signed char sA[128 * 128];
  __shared__ __align__(16) signed char sB[128 * 128];
  const int tid = threadIdx.x;
  const int w = tid >> 6;
  const int l = tid & 63;
  const int wm = w >> 1, wn = w & 1;
  const long bm0 = (long)blockIdx.y * 128;
  const long bn0 = (long)blockIdx.x * 128;

  i32x4 acc[4][4] = {};

  const int srow = l >> 3;         // row-within-chunk 0..7
  const int scol = (l & 7) * 16;   // starting byte col (16B per lane)

  for (int kt = 0; kt < K; kt += 128) {
    __syncthreads();  // previous tile's LDS reads done
#pragma unroll
    for (int i = 0; i < 4; ++i) {
      const int c = w * 4 + i;  // chunk: 8 rows = 1KB of LDS
      const int row = c * 8 + srow;
      gload_lds16(A + (bm0 + row) * K + kt + scol, &sA[c * 1024]);
      gload_lds16(B + (bn0 + row) * K + kt + scol, &sB[c * 1024]);
    }
    __syncthreads();  // staging visible (compiler drains vmcnt)
#pragma unroll
    for (int kk = 0; kk < 2; ++kk) {
      i32x4 af[4], bg[4];
#pragma unroll
      for (int m = 0; m < 4; ++m)
        af[m] = *(const i32x4*)&sA[(wm * 64 + m * 16 + (l & 15)) * 128 +
                                   kk * 64 + (l >> 4) * 16];
#pragma unroll
      for (int n = 0; n < 4; ++n)
        bg[n] = *(const i32x4*)&sB[(wn * 64 + n * 16 + (l & 15)) * 128 +
                                   kk * 64 + (l >> 4) * 16];
#pragma unroll
      for (int m = 0; m < 4; ++m)
#pragma unroll
        for (int n = 0; n < 4; ++n)
          acc[m][n] = __builtin_amdgcn_mfma_i32_16x16x64_i8(af[m], bg[n],
                                                            acc[m][n], 0, 0, 0);
    }
  }

  const float a1 = means[0];
  const float a2 = means[1];
  const float inv_a2 = means[2];

#pragma unroll
  for (int n = 0; n < 4; ++n) {
    const long cc = bn0 + wn * 64 + n * 16 + (l & 15);
    const float aw = alphaw[cc];
    const float bs = bias[cc];
#pragma unroll
    for (int m = 0; m < 4; ++m) {
#pragma unroll
      for (int rg = 0; rg < 4; ++rg) {
        const long r = bm0 + wm * 64 + m * 16 + (l >> 4) * 4 + rg;
        const float f = (float)acc[m][n][rg];  // exact: |acc| < 2^18
        if (EPI == 1) {
          // dequant (fma ok: ulp-level diffs cannot flip quant ties enough
          // to breach the output threshold -- see analysis)
          float t = fmaf(f * aw, a1, bs);
          // exact-formula GELU via fast erf, then clip
          float g = 0.5f * t * (1.0f + erf_fast(t * 0.70710678118654752f));
          g = fminf(fmaxf(g, -10.0f), 10.0f);
          float qv = g * inv_a2;
          qv = fminf(fmaxf(qv, -8.0f), 7.0f);
          qv = rintf(qv);
          out_b[r * N + cc] = (signed char)(int)qv;
        } else {
          // bit-exact numpy chain: (x*aw)*a2 + b, no FMA contraction
          float t = __fmul_rn(f, aw);
          t = __fmul_rn(t, a2);
          t = __fadd_rn(t, bs);
          out_f[r * N + cc] = t;
        }
      }
    }
  }
}

extern "C" void kernel_launch(void* const* d_in, const int* in_sizes, int n_in,
                              void* d_out, int out_size, void* d_ws,
                              size_t ws_size, hipStream_t stream) {
  const float* x0 = (const float*)d_in[0];
  const float* w1 = (const float*)d_in[1];
  const float* b1 = (const float*)d_in[2];
  const float* aw1 = (const float*)d_in[3];
  const float* aa1 = (const float*)d_in[4];
  const float* w2 = (const float*)d_in[5];
  const float* b2 = (const float*)d_in[6];
  const float* aw2 = (const float*)d_in[7];
  const float* aa2 = (const float*)d_in[8];

  char* ws = (char*)d_ws;
  float* means = (float*)ws;
  signed char* xq = (signed char*)(ws + 256);
  signed char* wq1 = (signed char*)(ws + 12583168);
  signed char* wq2 = (signed char*)(ws + 14942464);
  signed char* hq = (signed char*)(ws + 17301760);

  // 1) means of alpha_a1 / alpha_a2 (+ 1/a2)
  means_k<<<2, 256, 0, stream>>>(aa1, 768, aa2, 3072, means);
  // 2) quantize activations and weights to i8
  quant_x_k<<<12288, 256, 0, stream>>>(x0, (unsigned*)xq, means, 3145728);
  quant_w_k<<<2304, 256, 0, stream>>>(w1, aw1, (unsigned*)wq1, 768, 589824);
  quant_w_k<<<2304, 256, 0, stream>>>(w2, aw2, (unsigned*)wq2, 3072, 589824);
  // 3) GEMM1 [16384,768]x[3072,768]^T + gelu + requant -> hq (i8)
  dim3 g1(24, 128);
  gemm_k<1><<<g1, 256, 0, stream>>>(xq, wq1, aw1, b1, means, hq, nullptr, 3072,
                                    768);
  // 4) GEMM2 [16384,3072]x[768,3072]^T + bias -> out f32
  dim3 g2(6, 128);
  gemm_k<2><<<g2, 256, 0, stream>>>(hq, wq2, aw2, b2, means, nullptr,
                                    (float*)d_out, 768, 3072);
}

// Round 3
// 136.304 us; speedup vs baseline: 2.3668x; 1.4619x over previous
//
#include <hip/hip_runtime.h>
#include <hip/hip_bf16.h>
#include <math.h>

// ---------------------------------------------------------------------------
// Q_Mlp: x0 -> int4-quant -> GEMM1(K=768) -> dequant+GELU+clip -> int4-quant
//        -> GEMM2(K=3072) -> dequant+bias -> out (f32)
// Quantized operands are integers in [-8,7]: exact in int8. i8 MFMA
// (16x16x64, 2x bf16 rate) with i32 accumulation (max |acc| < 2^18, exact).
//
// LDS bank-conflict fix (T2, rule #21 both-sides involution):
//   LDS tile [128 rows][128 bytes]; reads at fixed col across 16 rows were
//   16-way same-bank. Swizzle col ^= ((row&7)<<4). Staging pre-swizzles the
//   GLOBAL source col (global_load_lds dest must stay linear); the fragment
//   read applies the same XOR. Both XOR operands reduce to lane constants
//   ((l>>3)<<4 staging, (l&7)<<4 reading) -> zero instruction cost.
//
// Workspace layout (bytes):
//   [0,256)              : a1, a2, inv_a2, 0.5*inv_a2 (f32)
//   [256, +12582912)     : xq  i8 [16384][768]
//   [12583168, +2359296) : wq1 i8 [3072][768]
//   [14942464, +2359296) : wq2 i8 [768][3072]
//   [17301760, +50331648): hq  i8 [16384][3072]
// ---------------------------------------------------------------------------

typedef __attribute__((ext_vector_type(4))) int i32x4;

__device__ __forceinline__ void gload_lds16(const void* g, void* l) {
  __builtin_amdgcn_global_load_lds(
      (const __attribute__((address_space(1))) void*)g,
      (__attribute__((address_space(3))) void*)l, 16, 0, 0);
}

// quantize: round-half-even(clip(x/a, -8, 7)) -> int in [-8,7]
__device__ __forceinline__ int q4_i8(float x, float a) {
  float t = x / a;  // IEEE div, matches numpy
  t = fminf(fmaxf(t, -8.0f), 7.0f);
  t = rintf(t);  // RNE, matches np.round
  return (int)t;
}

// ---- means of alpha_a1 (768) and alpha_a2 (3072), f64 accumulate ----------
__global__ void means_k(const float* __restrict__ v1, int n1,
                        const float* __restrict__ v2, int n2,
                        float* __restrict__ out) {
  const float* src = blockIdx.x ? v2 : v1;
  const int n = blockIdx.x ? n2 : n1;
  __shared__ double red[256];
  double s = 0.0;
  for (int i = threadIdx.x; i < n; i += 256) s += (double)src[i];
  red[threadIdx.x] = s;
  __syncthreads();
  for (int st = 128; st > 0; st >>= 1) {
    if (threadIdx.x < st) red[threadIdx.x] += red[threadIdx.x + st];
    __syncthreads();
  }
  if (threadIdx.x == 0) {
    float m = (float)(red[0] / (double)n);
    out[blockIdx.x] = m;
    if (blockIdx.x == 1) {
      out[2] = 1.0f / m;
      out[3] = 0.5f * (1.0f / m);
    }
  }
}

// ---- quantize activations x0 -> xq i8 -------------------------------------
__global__ void quant_x_k(const float* __restrict__ x,
                          unsigned* __restrict__ xq,
                          const float* __restrict__ means, int n4) {
  int i = blockIdx.x * blockDim.x + threadIdx.x;
  if (i >= n4) return;
  const float a = means[0];
  float4 v = ((const float4*)x)[i];
  unsigned u = (q4_i8(v.x, a) & 0xFF) | ((q4_i8(v.y, a) & 0xFF) << 8) |
               ((q4_i8(v.z, a) & 0xFF) << 16) | ((q4_i8(v.w, a) & 0xFF) << 24);
  xq[i] = u;
}

// ---- quantize weights [R][C] with per-row alpha ---------------------------
__global__ void quant_w_k(const float* __restrict__ w,
                          const float* __restrict__ alpha,
                          unsigned* __restrict__ wq, int C, int n4) {
  int i = blockIdx.x * blockDim.x + threadIdx.x;
  if (i >= n4) return;
  int row = (i * 4) / C;
  const float a = alpha[row];
  float4 v = ((const float4*)w)[i];
  unsigned u = (q4_i8(v.x, a) & 0xFF) | ((q4_i8(v.y, a) & 0xFF) << 8) |
               ((q4_i8(v.z, a) & 0xFF) << 16) | ((q4_i8(v.w, a) & 0xFF) << 24);
  wq[i] = u;
}

// ---- GEMM: C[M,N] = A[M,K] * B[N,K]^T, i8 MFMA 16x16x64, BK=128 -----------
// 128x128 tile, 256 threads (4 waves 2x2), 2-barrier loop, global_load_lds,
// XOR-swizzled LDS (see header).
// EPI==1: dequant+bias -> gelu(exact-erf approx) -> quant(a2) -> i8 hq
// EPI==2: dequant(a2,alpha_w2)+bias -> f32 out (bit-exact numpy chain)
template <int EPI>
__global__ __launch_bounds__(256, 4) void gemm_k(
    const signed char* __restrict__ A, const signed char* __restrict__ B,
    const float* __restrict__ alphaw, const float* __restrict__ bias,
    const float* __restrict__ means, signed char* __restrict__ out_b,
    float* __restrict__ out_f, int N, int K) {
  __shared__ __align__(16) signed char sA[128 * 128];
  __shared__ __align__(16) signed char sB[128 * 128];
  const int tid = threadIdx.x;
  const int w = tid >> 6;
  const int l = tid & 63;
  const int wm = w >> 1, wn = w & 1;
  const long bm0 = (long)blockIdx.y * 128;
  const long bn0 = (long)blockIdx.x * 128;

  i32x4 acc[4][4] = {};

  const int srow = l >> 3;                              // row-within-chunk 0..7
  const int scol = ((l & 7) * 16) ^ (srow << 4);        // pre-swizzled src col
  const int rsw = (l & 7) << 4;                         // read-side XOR

  for (int kt = 0; kt < K; kt += 128) {
    __syncthreads();  // previous tile's LDS reads done
#pragma unroll
    for (int i = 0; i < 4; ++i) {
      const int c = w * 4 + i;  // chunk: 8 rows = 1KB of LDS
      const int row = c * 8 + srow;
      gload_lds16(A + (bm0 + row) * K + kt + scol, &sA[c * 1024]);
      gload_lds16(B + (bn0 + row) * K + kt + scol, &sB[c * 1024]);
    }
    __syncthreads();  // staging visible (compiler drains vmcnt)
#pragma unroll
    for (int kk = 0; kk < 2; ++kk) {
      const int kc = (kk * 64 + (l >> 4) * 16) ^ rsw;  // swizzled k-col
      i32x4 af[4], bg[4];
#pragma unroll
      for (int m = 0; m < 4; ++m)
        af[m] = *(const i32x4*)&sA[(wm * 64 + m * 16 + (l & 15)) * 128 + kc];
#pragma unroll
      for (int n = 0; n < 4; ++n)
        bg[n] = *(const i32x4*)&sB[(wn * 64 + n * 16 + (l & 15)) * 128 + kc];
#pragma unroll
      for (int m = 0; m < 4; ++m)
#pragma unroll
        for (int n = 0; n < 4; ++n)
          acc[m][n] = __builtin_amdgcn_mfma_i32_16x16x64_i8(af[m], bg[n],
                                                            acc[m][n], 0, 0, 0);
    }
  }

  const float a1 = means[0];
  const float a2 = means[1];
  const float half_inv_a2 = means[3];

  // hoist per-column constants (4 columns per thread)
  float awc[4], bsc[4];
  const int cc0 = (int)bn0 + wn * 64 + (l & 15);
#pragma unroll
  for (int n = 0; n < 4; ++n) {
    awc[n] = alphaw[cc0 + n * 16];
    bsc[n] = bias[cc0 + n * 16];
  }

  const int r0 = (int)bm0 + wm * 64 + (l >> 4) * 4;

  if (EPI == 1) {
    float awa1[4];
#pragma unroll
    for (int n = 0; n < 4; ++n) awa1[n] = awc[n] * a1;
#pragma unroll
    for (int m = 0; m < 4; ++m) {
#pragma unroll
      for (int rg = 0; rg < 4; ++rg) {
        const int r = r0 + m * 16 + rg;
        signed char* prow = out_b + (size_t)r * N + cc0;
#pragma unroll
        for (int n = 0; n < 4; ++n) {
          const float f = (float)acc[m][n][rg];  // exact: |acc| < 2^18
          const float t = fmaf(f, awa1[n], bsc[n]);
          // exact-formula GELU via A&S 7.1.26 erf (|err|<=1.5e-7)
          const float x = t * 0.70710678118654752f;
          const float az = fabsf(x);
          const float rr = __builtin_amdgcn_rcpf(fmaf(0.3275911f, az, 1.0f));
          float p = fmaf(rr, 1.061405429f, -1.453152027f);
          p = fmaf(rr, p, 1.421413741f);
          p = fmaf(rr, p, -0.284496736f);
          p = fmaf(rr, p, 0.254829592f);
          p = p * rr;
          const float e = __expf(-az * az);
          float er = fmaf(-p, e, 1.0f);
          er = copysignf(er, x);
          // +/-10 clip dropped: 10/a2 > 7 always, saturation identical
          float qv = t * (1.0f + er) * half_inv_a2;
          qv = fminf(fmaxf(qv, -8.0f), 7.0f);
          qv = rintf(qv);
          prow[n * 16] = (signed char)(int)qv;
        }
      }
    }
  } else {
#pragma unroll
    for (int m = 0; m < 4; ++m) {
#pragma unroll
      for (int rg = 0; rg < 4; ++rg) {
        const int r = r0 + m * 16 + rg;
        float* prow = out_f + (size_t)r * N + cc0;
#pragma unroll
        for (int n = 0; n < 4; ++n) {
          const float f = (float)acc[m][n][rg];
          // bit-exact numpy chain: ((x*aw)*a2) + b, no FMA contraction
          float t = __fmul_rn(f, awc[n]);
          t = __fmul_rn(t, a2);
          t = __fadd_rn(t, bsc[n]);
          prow[n * 16] = t;
        }
      }
    }
  }
}

extern "C" void kernel_launch(void* const* d_in, const int* in_sizes, int n_in,
                              void* d_out, int out_size, void* d_ws,
                              size_t ws_size, hipStream_t stream) {
  const float* x0 = (const float*)d_in[0];
  const float* w1 = (const float*)d_in[1];
  const float* b1 = (const float*)d_in[2];
  const float* aw1 = (const float*)d_in[3];
  const float* aa1 = (const float*)d_in[4];
  const float* w2 = (const float*)d_in[5];
  const float* b2 = (const float*)d_in[6];
  const float* aw2 = (const float*)d_in[7];
  const float* aa2 = (const float*)d_in[8];

  char* ws = (char*)d_ws;
  float* means = (float*)ws;
  signed char* xq = (signed char*)(ws + 256);
  signed char* wq1 = (signed char*)(ws + 12583168);
  signed char* wq2 = (signed char*)(ws + 14942464);
  signed char* hq = (signed char*)(ws + 17301760);

  // 1) means of alpha_a1 / alpha_a2 (+ 1/a2, 0.5/a2)
  means_k<<<2, 256, 0, stream>>>(aa1, 768, aa2, 3072, means);
  // 2) quantize activations and weights to i8
  quant_x_k<<<12288, 256, 0, stream>>>(x0, (unsigned*)xq, means, 3145728);
  quant_w_k<<<2304, 256, 0, stream>>>(w1, aw1, (unsigned*)wq1, 768, 589824);
  quant_w_k<<<2304, 256, 0, stream>>>(w2, aw2, (unsigned*)wq2, 3072, 589824);
  // 3) GEMM1 [16384,768]x[3072,768]^T + gelu + requant -> hq (i8)
  dim3 g1(24, 128);
  gemm_k<1><<<g1, 256, 0, stream>>>(xq, wq1, aw1, b1, means, hq, nullptr, 3072,
                                    768);
  // 4) GEMM2 [16384,3072]x[768,3072]^T + bias -> out f32
  dim3 g2(6, 128);
  gemm_k<2><<<g2, 256, 0, stream>>>(hq, wq2, aw2, b2, means, nullptr,
                                    (float*)d_out, 768, 3072);
}